// Round 8
// baseline (383.219 us; speedup 1.0000x reference)
//
#include <hip/hip_runtime.h>
#include <cstdint>

// ======================= threefry-2x32 (JAX-compatible) =======================
__host__ __device__ inline void tf2x32(uint32_t k0, uint32_t k1,
                                       uint32_t x0, uint32_t x1,
                                       uint32_t& o0, uint32_t& o1) {
  uint32_t ks2 = k0 ^ k1 ^ 0x1BD11BDAu;
  uint32_t v0 = x0 + k0, v1 = x1 + k1;
#define TFR(r) { v0 += v1; v1 = (v1 << r) | (v1 >> (32 - r)); v1 ^= v0; }
  TFR(13) TFR(15) TFR(26) TFR(6)
  v0 += k1;  v1 += ks2 + 1u;
  TFR(17) TFR(29) TFR(16) TFR(24)
  v0 += ks2; v1 += k0 + 2u;
  TFR(13) TFR(15) TFR(26) TFR(6)
  v0 += k0;  v1 += k1 + 3u;
  TFR(17) TFR(29) TFR(16) TFR(24)
  v0 += k1;  v1 += ks2 + 4u;
  TFR(13) TFR(15) TFR(26) TFR(6)
  v0 += ks2; v1 += k0 + 5u;
#undef TFR
  o0 = v0; o1 = v1;
}

__device__ inline float erfinv32(float x) {
  float w = -log1pf(-x * x);
  float p;
  if (w < 5.0f) {
    w -= 2.5f;
    p = 2.81022636e-08f;
    p = fmaf(p, w, 3.43273939e-07f);
    p = fmaf(p, w, -3.5233877e-06f);
    p = fmaf(p, w, -4.39150654e-06f);
    p = fmaf(p, w, 0.00021858087f);
    p = fmaf(p, w, -0.00125372503f);
    p = fmaf(p, w, -0.00417768164f);
    p = fmaf(p, w, 0.246640727f);
    p = fmaf(p, w, 1.50140941f);
  } else {
    w = sqrtf(w) - 3.0f;
    p = -0.000200214257f;
    p = fmaf(p, w, 0.000100950558f);
    p = fmaf(p, w, 0.00134934322f);
    p = fmaf(p, w, -0.00367342844f);
    p = fmaf(p, w, 0.00573950773f);
    p = fmaf(p, w, -0.0076224613f);
    p = fmaf(p, w, 0.00943887047f);
    p = fmaf(p, w, 1.00167406f);
    p = fmaf(p, w, 2.83297682f);
  }
  return p * x;
}

__device__ inline float rng_normal(uint32_t k0, uint32_t k1, uint32_t idx) {
  uint32_t o0, o1;
  tf2x32(k0, k1, 0u, idx, o0, o1);
  uint32_t bits = o0 ^ o1;
  float f = __uint_as_float((bits >> 9) | 0x3f800000u) - 1.0f;
  const float lo = -0.999999940395355224609375f;
  float u = fmaxf(lo, f * 2.0f + lo);
  return 1.41421356237f * erfinv32(u);
}

struct RngKeys {
  uint32_t wA0, wA1, bA0, bA1;
  uint32_t wB0, wB1, bB0, bB1;
  uint32_t wC0, wC1, bC0, bC1;
  uint32_t wD0, wD1, bD0, bD1;
};

typedef _Float16 f16x8 __attribute__((ext_vector_type(8)));
typedef _Float16 f16x4 __attribute__((ext_vector_type(4)));
typedef float f32x4 __attribute__((ext_vector_type(4)));

// ======================= weight / bias sampling (f16 weights) =======================
__global__ __launch_bounds__(256) void gen_weights(
    const float* __restrict__ Awmu, const float* __restrict__ Awlv,
    const float* __restrict__ Dwmu, const float* __restrict__ Dwlv,
    const float* __restrict__ Bwmu, const float* __restrict__ Bwlv,
    const float* __restrict__ Cwmu, const float* __restrict__ Cwlv,
    _Float16* __restrict__ Wh, RngKeys kk) {
  uint32_t idx = blockIdx.x * 256u + threadIdx.x;  // [0, 3*2^20)
  uint32_t sel = idx >> 20;
  uint32_t e = idx & 0xFFFFFu;
  float w;
  if (sel == 0u) {
    w = Awmu[e] + expf(0.5f * Awlv[e]) * rng_normal(kk.wA0, kk.wA1, e)
      + Dwmu[e] + expf(0.5f * Dwlv[e]) * rng_normal(kk.wD0, kk.wD1, e);
  } else if (sel == 1u) {
    w = Bwmu[e] + expf(0.5f * Bwlv[e]) * rng_normal(kk.wB0, kk.wB1, e);
  } else {
    w = Cwmu[e] + expf(0.5f * Cwlv[e]) * rng_normal(kk.wC0, kk.wC1, e);
  }
  Wh[idx] = (_Float16)w;
}

__global__ __launch_bounds__(256) void gen_bias(
    const float* __restrict__ Abmu, const float* __restrict__ Ablv,
    const float* __restrict__ Dbmu, const float* __restrict__ Dblv,
    const float* __restrict__ Bbmu, const float* __restrict__ Bblv,
    const float* __restrict__ Cbmu, const float* __restrict__ Cblv,
    float* __restrict__ bcat, RngKeys kk) {
  uint32_t o = blockIdx.x * 256u + threadIdx.x;  // 0..3071
  uint32_t e = o & 1023u;
  float b;
  if (o < 1024u)
    b = Abmu[e] + expf(0.5f * Ablv[e]) * rng_normal(kk.bA0, kk.bA1, e)
      + Dbmu[e] + expf(0.5f * Dblv[e]) * rng_normal(kk.bD0, kk.bD1, e);
  else if (o < 2048u)
    b = Bbmu[e] + expf(0.5f * Bblv[e]) * rng_normal(kk.bB0, kk.bB1, e);
  else
    b = Cbmu[e] + expf(0.5f * Cblv[e]) * rng_normal(kk.bC0, kk.bC1, e);
  bcat[o] = b;
}

// ======================= x -> f16 =======================
__global__ __launch_bounds__(256) void convert_x(const float* __restrict__ X,
                                                 _Float16* __restrict__ Xh) {
  size_t i4 = ((size_t)blockIdx.x * 256 + threadIdx.x) * 4;
  float4 v = *(const float4*)(X + i4);
  f16x4 h;
  h[0] = (_Float16)v.x; h[1] = (_Float16)v.y;
  h[2] = (_Float16)v.z; h[3] = (_Float16)v.w;
  *(f16x4*)(Xh + i4) = h;
}

// ======================= f16 MFMA GEMM + fused epilogue =======================
// ROUND-8: r0 structure with BK 32->64. Halves the per-K-step barrier-drain
// count (32->16 iters) while doubling MFMA per drain (32/wave). Occupancy is
// PRESERVED (the thing r1-r4 broke): fragment registers are reused across
// the two 32-k halves (read half0 -> 16 MFMA -> read half1 into the same
// regs (overlaps half0's MFMAs) -> 16 MFMA), so peak regs ~120 <= 128 ->
// 4 waves/SIMD / 4 blk/CU as before. LDS 2x16KB = 32KB/blk x 4 = 128 <= 160.
// Swizzle per 32-k half identical to r0's measured-0-conflict pattern.
// Accumulation order == two consecutive r0 iterations: bit-identical.
// C[M=16384, N=3072] = X[M,K=1024] * W[N,K]^T, single-pass f16 MFMA.
// seg 0 (n<1024):        Z[m*2048 + n]        = f16(exp(-exp(v + bias)))   (E)
// seg 1 (1024<=n<2048):  Z[m*2048 + n]        = f16((v+bias) * x[m][n-1024]) (Bx)
// seg 2 (n>=2048):       out[m*1024 + n-2048] = v + bias  (f32)            (C)
__device__ inline void gl2lds16(const void* g, void* l) {
  __builtin_amdgcn_global_load_lds(
      (const __attribute__((address_space(1))) void*)g,
      (__attribute__((address_space(3))) void*)l, 16, 0, 0);
}

__global__ __launch_bounds__(256, 4) void gemm_fused(
    const _Float16* __restrict__ Xh, const _Float16* __restrict__ Wh,
    const float* __restrict__ X, const float* __restrict__ bcat,
    _Float16* __restrict__ Z, float* __restrict__ out) {
  __shared__ _Float16 sA[128 * 64];  // 16 KB: [row][8 slots x 8 f16]
  __shared__ _Float16 sB[128 * 64];  // 16 KB

  const int tid = threadIdx.x;
  const int m0 = blockIdx.y * 128;
  const int n0 = blockIdx.x * 128;

  // staging: thread t -> row srow=t>>3 (+32 per round, 4 rounds), slot t&7
  // (half = (t>>2)&1, s4 = t&3). Stored slot (half,s4) of row r holds global
  // chunk half*4 + (s4 ^ ((r>>1)&3))  [(r>>1)&3 invariant under r+=32].
  const int srow = tid >> 3;
  const int cg = ((tid >> 2) & 1) * 4 + ((tid & 3) ^ ((srow >> 1) & 3));
  const _Float16* gA = Xh + (size_t)(m0 + srow) * 1024 + cg * 8;
  const _Float16* gB = Wh + (size_t)(n0 + srow) * 1024 + cg * 8;
  char* lA = (char*)sA + tid * 16;
  char* lB = (char*)sB + tid * 16;

  const int lane = tid & 63;
  const int wave = tid >> 6;
  const int wm = wave >> 1, wn = wave & 1;
  const int fr = lane & 15;  // m/n within a 16-tile
  const int q = lane >> 4;   // k-chunk within a 32-k half
  const int sw8 = (q ^ ((fr >> 1) & 3)) * 8;  // swizzled slot offset (f16)

  f32x4 acc[4][4] = {};

  for (int k0 = 0; k0 < 1024; k0 += 64) {
    __syncthreads();  // previous iter's ds_reads done before overwrite
    gl2lds16(gA + k0,              lA);
    gl2lds16(gA + 32 * 1024 + k0,  lA + 4096);
    gl2lds16(gA + 64 * 1024 + k0,  lA + 8192);
    gl2lds16(gA + 96 * 1024 + k0,  lA + 12288);
    gl2lds16(gB + k0,              lB);
    gl2lds16(gB + 32 * 1024 + k0,  lB + 4096);
    gl2lds16(gB + 64 * 1024 + k0,  lB + 8192);
    gl2lds16(gB + 96 * 1024 + k0,  lB + 12288);
    __syncthreads();  // compiler drains vmcnt before barrier

    f16x8 ah[4], bh[4];
    // ---- half 0 (k0 .. k0+31): slots 0-3 ----
#pragma unroll
    for (int t = 0; t < 4; ++t) {
      ah[t] = *(const f16x8*)&sA[(wm * 64 + t * 16 + fr) * 64 + sw8];
      bh[t] = *(const f16x8*)&sB[(wn * 64 + t * 16 + fr) * 64 + sw8];
    }
#pragma unroll
    for (int mt = 0; mt < 4; ++mt)
#pragma unroll
      for (int nt = 0; nt < 4; ++nt)
        acc[mt][nt] = __builtin_amdgcn_mfma_f32_16x16x32_f16(
            ah[mt], bh[nt], acc[mt][nt], 0, 0, 0);
    // ---- half 1 (k0+32 .. k0+63): slots 4-7; reuse frag regs ----
#pragma unroll
    for (int t = 0; t < 4; ++t) {
      ah[t] = *(const f16x8*)&sA[(wm * 64 + t * 16 + fr) * 64 + 32 + sw8];
      bh[t] = *(const f16x8*)&sB[(wn * 64 + t * 16 + fr) * 64 + 32 + sw8];
    }
#pragma unroll
    for (int mt = 0; mt < 4; ++mt)
#pragma unroll
      for (int nt = 0; nt < 4; ++nt)
        acc[mt][nt] = __builtin_amdgcn_mfma_f32_16x16x32_f16(
            ah[mt], bh[nt], acc[mt][nt], 0, 0, 0);
  }

  // epilogue: C/D layout col(n)=lane&15, row(m)=(lane>>4)*4+reg
  const int seg = n0 >> 10;  // block-uniform
  const int mrow = (lane >> 4) * 4;
#pragma unroll
  for (int nt = 0; nt < 4; ++nt) {
    int n = n0 + wn * 64 + nt * 16 + fr;
    float bv = bcat[n];
#pragma unroll
    for (int mt = 0; mt < 4; ++mt) {
      int mbase = m0 + wm * 64 + mt * 16 + mrow;
      f32x4 a = acc[mt][nt];
#pragma unroll
      for (int r = 0; r < 4; ++r) {
        int m = mbase + r;
        float v = a[r] + bv;
        if (seg == 0) {
          Z[(size_t)m * 2048 + n] = (_Float16)expf(-expf(v));
        } else if (seg == 1) {
          Z[(size_t)m * 2048 + n] =
              (_Float16)(v * X[(size_t)m * 1024 + (n - 1024)]);
        } else {
          out[(size_t)m * 1024 + (n - 2048)] = v;
        }
      }
    }
  }
}

// ======================= chunked linear-recurrence scan =======================
// r3 scan kernels verbatim (tail = 191 us measured, session best).
#define LSEQ 4096
#define NC 64
#define LC 64
#define ZW 2048

// vectorized: 4 n's per thread (f16x4 = 8B loads, float4 stores), 256 thr
__global__ __launch_bounds__(256) void scan_chunk(const _Float16* __restrict__ Z,
                                                  float* __restrict__ ac,
                                                  float* __restrict__ uc) {
  int n4 = threadIdx.x * 4;
  int c = blockIdx.y;
  int b = blockIdx.z;
  const _Float16* base = Z + (size_t)(b * LSEQ + c * LC) * ZW;
  float a[4] = {1.0f, 1.0f, 1.0f, 1.0f};
  float u[4] = {0.0f, 0.0f, 0.0f, 0.0f};
#pragma unroll 4
  for (int l = 0; l < LC; ++l) {
    f16x4 ev = *(const f16x4*)&base[(size_t)l * ZW + n4];
    f16x4 bx = *(const f16x4*)&base[(size_t)l * ZW + 1024 + n4];
#pragma unroll
    for (int i = 0; i < 4; ++i) {
      float e = (float)ev[i];
      a[i] *= e;
      u[i] = fmaf(e, u[i], (float)bx[i]);
    }
  }
  size_t o = ((size_t)b * NC + c) * 1024 + n4;
  *(float4*)&ac[o] = make_float4(a[0], a[1], a[2], a[3]);
  *(float4*)&uc[o] = make_float4(u[0], u[1], u[2], u[3]);
}

__global__ __launch_bounds__(256) void scan_prefix(const float* __restrict__ ac,
                                                   const float* __restrict__ uc,
                                                   float* __restrict__ hin) {
  int idx = blockIdx.x * 256 + threadIdx.x;  // 0..4095
  int b = idx >> 10, n = idx & 1023;
  float h = 0.0f;
  for (int c = 0; c < NC; ++c) {
    size_t o = ((size_t)b * NC + c) * 1024 + n;
    hin[o] = h;
    h = fmaf(ac[o], h, uc[o]);
  }
}

__global__ __launch_bounds__(256) void scan_final(const _Float16* __restrict__ Z,
                                                  const float* __restrict__ hin,
                                                  float* __restrict__ out) {
  int n4 = threadIdx.x * 4;
  int c = blockIdx.y;
  int b = blockIdx.z;
  const _Float16* base = Z + (size_t)(b * LSEQ + c * LC) * ZW;
  float* obase = out + (size_t)(b * LSEQ + c * LC) * 1024;
  size_t ho = ((size_t)b * NC + c) * 1024 + n4;
  float4 hv = *(const float4*)&hin[ho];
  float h[4] = {hv.x, hv.y, hv.z, hv.w};
#pragma unroll 4
  for (int l = 0; l < LC; ++l) {
    f16x4 ev = *(const f16x4*)&base[(size_t)l * ZW + n4];
    f16x4 bx = *(const f16x4*)&base[(size_t)l * ZW + 1024 + n4];
    float4 cc = *(const float4*)&obase[(size_t)l * 1024 + n4];
#pragma unroll
    for (int i = 0; i < 4; ++i)
      h[i] = fmaf((float)ev[i], h[i], (float)bx[i]);
    *(float4*)&obase[(size_t)l * 1024 + n4] =
        make_float4(cc.x * h[0] * 4.0f, cc.y * h[1] * 4.0f,
                    cc.z * h[2] * 4.0f, cc.w * h[3] * 4.0f);
  }
}

// ======================= launch =======================
extern "C" void kernel_launch(void* const* d_in, const int* in_sizes, int n_in,
                              void* d_out, int out_size, void* d_ws, size_t ws_size,
                              hipStream_t stream) {
  const float* x    = (const float*)d_in[0];
  const float* Awmu = (const float*)d_in[1];
  const float* Awlv = (const float*)d_in[2];
  const float* Abmu = (const float*)d_in[3];
  const float* Ablv = (const float*)d_in[4];
  const float* Bwmu = (const float*)d_in[5];
  const float* Bwlv = (const float*)d_in[6];
  const float* Bbmu = (const float*)d_in[7];
  const float* Bblv = (const float*)d_in[8];
  const float* Cwmu = (const float*)d_in[9];
  const float* Cwlv = (const float*)d_in[10];
  const float* Cbmu = (const float*)d_in[11];
  const float* Cblv = (const float*)d_in[12];
  const float* Dwmu = (const float*)d_in[13];
  const float* Dwlv = (const float*)d_in[14];
  const float* Dbmu = (const float*)d_in[15];
  const float* Dblv = (const float*)d_in[16];

  uint32_t k4[4][2];
  for (uint32_t i = 0; i < 4; ++i)
    tf2x32(0u, 42u, 0u, i, k4[i][0], k4[i][1]);  // kA,kB,kC,kdt
  RngKeys kk;
  tf2x32(k4[0][0], k4[0][1], 0u, 0u, kk.wA0, kk.wA1);
  tf2x32(k4[0][0], k4[0][1], 0u, 1u, kk.bA0, kk.bA1);
  tf2x32(k4[1][0], k4[1][1], 0u, 0u, kk.wB0, kk.wB1);
  tf2x32(k4[1][0], k4[1][1], 0u, 1u, kk.bB0, kk.bB1);
  tf2x32(k4[2][0], k4[2][1], 0u, 0u, kk.wC0, kk.wC1);
  tf2x32(k4[2][0], k4[2][1], 0u, 1u, kk.bC0, kk.bC1);
  tf2x32(k4[3][0], k4[3][1], 0u, 0u, kk.wD0, kk.wD1);
  tf2x32(k4[3][0], k4[3][1], 0u, 1u, kk.bD0, kk.bD1);

  // workspace layout (~104 MiB live)
  // Scan temporaries (ac/uc/hin) ALIAS the Xh region: Xh is consumed only by
  // gemm_fused, which completes before scan_chunk; convert_x fully rewrites
  // Xh next iteration.
  char* ws = (char*)d_ws;
  const size_t OFF_WH   = 0;                    // 3072*1024*2 = 6 MiB
  const size_t OFF_BCAT = 6291456;              // 3072 f32
  const size_t OFF_XH   = 8388608;              // 16384*1024*2 = 32 MiB
  const size_t OFF_Z    = 41943040;             // 16384*2048*2 = 64 MiB
  const size_t OFF_AC   = OFF_XH;               // 4*NC*1024*4 = 1 MiB
  const size_t OFF_UC   = OFF_XH + 2097152;
  const size_t OFF_HIN  = OFF_XH + 4194304;
  const size_t NEEDED   = OFF_Z + (size_t)16384 * 2048 * 2;
  if (ws_size < NEEDED) return;

  _Float16* Wh  = (_Float16*)(ws + OFF_WH);
  float*    bcat= (float*)(ws + OFF_BCAT);
  _Float16* Xh  = (_Float16*)(ws + OFF_XH);
  _Float16* Z   = (_Float16*)(ws + OFF_Z);
  float*    ac  = (float*)(ws + OFF_AC);
  float*    ucv = (float*)(ws + OFF_UC);
  float*    hin = (float*)(ws + OFF_HIN);
  float*    out = (float*)d_out;

  gen_weights<<<dim3(12288), dim3(256), 0, stream>>>(
      Awmu, Awlv, Dwmu, Dwlv, Bwmu, Bwlv, Cwmu, Cwlv, Wh, kk);
  gen_bias<<<dim3(12), dim3(256), 0, stream>>>(
      Abmu, Ablv, Dbmu, Dblv, Bbmu, Bblv, Cbmu, Cblv, bcat, kk);
  convert_x<<<dim3(16384), dim3(256), 0, stream>>>(x, Xh);
  gemm_fused<<<dim3(24, 128), dim3(256), 0, stream>>>(
      Xh, Wh, x, bcat, Z, out);
  scan_chunk<<<dim3(1, NC, 4), dim3(256), 0, stream>>>(Z, ac, ucv);
  scan_prefix<<<dim3(16), dim3(256), 0, stream>>>(ac, ucv, hin);
  scan_final<<<dim3(1, NC, 4), dim3(256), 0, stream>>>(Z, hin, out);
}

// Round 9
// 371.641 us; speedup vs baseline: 1.0312x; 1.0312x over previous
//
#include <hip/hip_runtime.h>
#include <cstdint>

// ======================= threefry-2x32 (JAX-compatible) =======================
__host__ __device__ inline void tf2x32(uint32_t k0, uint32_t k1,
                                       uint32_t x0, uint32_t x1,
                                       uint32_t& o0, uint32_t& o1) {
  uint32_t ks2 = k0 ^ k1 ^ 0x1BD11BDAu;
  uint32_t v0 = x0 + k0, v1 = x1 + k1;
#define TFR(r) { v0 += v1; v1 = (v1 << r) | (v1 >> (32 - r)); v1 ^= v0; }
  TFR(13) TFR(15) TFR(26) TFR(6)
  v0 += k1;  v1 += ks2 + 1u;
  TFR(17) TFR(29) TFR(16) TFR(24)
  v0 += ks2; v1 += k0 + 2u;
  TFR(13) TFR(15) TFR(26) TFR(6)
  v0 += k0;  v1 += k1 + 3u;
  TFR(17) TFR(29) TFR(16) TFR(24)
  v0 += k1;  v1 += ks2 + 4u;
  TFR(13) TFR(15) TFR(26) TFR(6)
  v0 += ks2; v1 += k0 + 5u;
#undef TFR
  o0 = v0; o1 = v1;
}

__device__ inline float erfinv32(float x) {
  float w = -log1pf(-x * x);
  float p;
  if (w < 5.0f) {
    w -= 2.5f;
    p = 2.81022636e-08f;
    p = fmaf(p, w, 3.43273939e-07f);
    p = fmaf(p, w, -3.5233877e-06f);
    p = fmaf(p, w, -4.39150654e-06f);
    p = fmaf(p, w, 0.00021858087f);
    p = fmaf(p, w, -0.00125372503f);
    p = fmaf(p, w, -0.00417768164f);
    p = fmaf(p, w, 0.246640727f);
    p = fmaf(p, w, 1.50140941f);
  } else {
    w = sqrtf(w) - 3.0f;
    p = -0.000200214257f;
    p = fmaf(p, w, 0.000100950558f);
    p = fmaf(p, w, 0.00134934322f);
    p = fmaf(p, w, -0.00367342844f);
    p = fmaf(p, w, 0.00573950773f);
    p = fmaf(p, w, -0.0076224613f);
    p = fmaf(p, w, 0.00943887047f);
    p = fmaf(p, w, 1.00167406f);
    p = fmaf(p, w, 2.83297682f);
  }
  return p * x;
}

__device__ inline float rng_normal(uint32_t k0, uint32_t k1, uint32_t idx) {
  uint32_t o0, o1;
  tf2x32(k0, k1, 0u, idx, o0, o1);
  uint32_t bits = o0 ^ o1;
  float f = __uint_as_float((bits >> 9) | 0x3f800000u) - 1.0f;
  const float lo = -0.999999940395355224609375f;
  float u = fmaxf(lo, f * 2.0f + lo);
  return 1.41421356237f * erfinv32(u);
}

struct RngKeys {
  uint32_t wA0, wA1, bA0, bA1;
  uint32_t wB0, wB1, bB0, bB1;
  uint32_t wC0, wC1, bC0, bC1;
  uint32_t wD0, wD1, bD0, bD1;
};

typedef _Float16 f16x8 __attribute__((ext_vector_type(8)));
typedef _Float16 f16x4 __attribute__((ext_vector_type(4)));
typedef float f32x4 __attribute__((ext_vector_type(4)));

// ======================= weight / bias sampling (f16 weights) =======================
__global__ __launch_bounds__(256) void gen_weights(
    const float* __restrict__ Awmu, const float* __restrict__ Awlv,
    const float* __restrict__ Dwmu, const float* __restrict__ Dwlv,
    const float* __restrict__ Bwmu, const float* __restrict__ Bwlv,
    const float* __restrict__ Cwmu, const float* __restrict__ Cwlv,
    _Float16* __restrict__ Wh, RngKeys kk) {
  uint32_t idx = blockIdx.x * 256u + threadIdx.x;  // [0, 3*2^20)
  uint32_t sel = idx >> 20;
  uint32_t e = idx & 0xFFFFFu;
  float w;
  if (sel == 0u) {
    w = Awmu[e] + expf(0.5f * Awlv[e]) * rng_normal(kk.wA0, kk.wA1, e)
      + Dwmu[e] + expf(0.5f * Dwlv[e]) * rng_normal(kk.wD0, kk.wD1, e);
  } else if (sel == 1u) {
    w = Bwmu[e] + expf(0.5f * Bwlv[e]) * rng_normal(kk.wB0, kk.wB1, e);
  } else {
    w = Cwmu[e] + expf(0.5f * Cwlv[e]) * rng_normal(kk.wC0, kk.wC1, e);
  }
  Wh[idx] = (_Float16)w;
}

__global__ __launch_bounds__(256) void gen_bias(
    const float* __restrict__ Abmu, const float* __restrict__ Ablv,
    const float* __restrict__ Dbmu, const float* __restrict__ Dblv,
    const float* __restrict__ Bbmu, const float* __restrict__ Bblv,
    const float* __restrict__ Cbmu, const float* __restrict__ Cblv,
    float* __restrict__ bcat, RngKeys kk) {
  uint32_t o = blockIdx.x * 256u + threadIdx.x;  // 0..3071
  uint32_t e = o & 1023u;
  float b;
  if (o < 1024u)
    b = Abmu[e] + expf(0.5f * Ablv[e]) * rng_normal(kk.bA0, kk.bA1, e)
      + Dbmu[e] + expf(0.5f * Dblv[e]) * rng_normal(kk.bD0, kk.bD1, e);
  else if (o < 2048u)
    b = Bbmu[e] + expf(0.5f * Bblv[e]) * rng_normal(kk.bB0, kk.bB1, e);
  else
    b = Cbmu[e] + expf(0.5f * Cblv[e]) * rng_normal(kk.bC0, kk.bC1, e);
  bcat[o] = b;
}

// ======================= x -> f16 =======================
__global__ __launch_bounds__(256) void convert_x(const float* __restrict__ X,
                                                 _Float16* __restrict__ Xh) {
  size_t i4 = ((size_t)blockIdx.x * 256 + threadIdx.x) * 4;
  float4 v = *(const float4*)(X + i4);
  f16x4 h;
  h[0] = (_Float16)v.x; h[1] = (_Float16)v.y;
  h[2] = (_Float16)v.z; h[3] = (_Float16)v.w;
  *(f16x4*)(Xh + i4) = h;
}

// ======================= f16 MFMA GEMM + fused epilogue =======================
// ROUND-9: r8 (BK=64, 16 iters, 4 blk/CU -- gemm 186->165 us) with the bank
// conflicts FIXED. r8's single [128][64] tile has 128-B rows = every row
// starts at bank 0 -> ~8-way aliasing (12.6M conflict-cycles ~ 20 us/CU
// serialized). Fix: TWO separate 8 KB [128][32] buffers per operand, each
// bank-wise IDENTICAL to r0's measured-0-conflict layout (64-B row stride
// alternates rows across bank halves; chunk swizzle (t&3)^((srow>>1)&3);
// read swizzle q^((fr>>1)&3)). Half h stages/reads cols k0+32h..k0+32h+31
// from sX[h]. Same 8 gl2lds/thread/iter, same 32 KB LDS (4 blk/CU), same
// accumulation order as r8 (passed): bit-identical numerics.
// C[M=16384, N=3072] = X[M,K=1024] * W[N,K]^T, single-pass f16 MFMA.
// seg 0 (n<1024):        Z[m*2048 + n]        = f16(exp(-exp(v + bias)))   (E)
// seg 1 (1024<=n<2048):  Z[m*2048 + n]        = f16((v+bias) * x[m][n-1024]) (Bx)
// seg 2 (n>=2048):       out[m*1024 + n-2048] = v + bias  (f32)            (C)
__device__ inline void gl2lds16(const void* g, void* l) {
  __builtin_amdgcn_global_load_lds(
      (const __attribute__((address_space(1))) void*)g,
      (__attribute__((address_space(3))) void*)l, 16, 0, 0);
}

__global__ __launch_bounds__(256, 4) void gemm_fused(
    const _Float16* __restrict__ Xh, const _Float16* __restrict__ Wh,
    const float* __restrict__ X, const float* __restrict__ bcat,
    _Float16* __restrict__ Z, float* __restrict__ out) {
  __shared__ _Float16 sA0[128 * 32];  // 8 KB, r0 layout, k-half 0
  __shared__ _Float16 sA1[128 * 32];  // 8 KB, k-half 1
  __shared__ _Float16 sB0[128 * 32];
  __shared__ _Float16 sB1[128 * 32];  // total 32 KB -> 4 blk/CU

  const int tid = threadIdx.x;
  const int m0 = blockIdx.y * 128;
  const int n0 = blockIdx.x * 128;

  // staging (r0 pattern): thread t -> row t>>2 (+64 for 2nd load), stored
  // slot t&3 holds global chunk (t&3)^((row>>1)&3) within each 32-k half.
  const int srow = tid >> 2;
  const int scg = (tid & 3) ^ ((srow >> 1) & 3);
  const _Float16* gA = Xh + (size_t)(m0 + srow) * 1024 + scg * 8;
  const _Float16* gB = Wh + (size_t)(n0 + srow) * 1024 + scg * 8;
  char* lA0 = (char*)sA0 + tid * 16;
  char* lA1 = (char*)sA1 + tid * 16;
  char* lB0 = (char*)sB0 + tid * 16;
  char* lB1 = (char*)sB1 + tid * 16;

  const int lane = tid & 63;
  const int wave = tid >> 6;
  const int wm = wave >> 1, wn = wave & 1;
  const int fr = lane & 15;  // m/n within a 16-tile
  const int q = lane >> 4;   // k-chunk (8 f16) within a 32-k half
  const int kc = q ^ ((fr >> 1) & 3);  // r0 swizzled k-chunk (lane-constant)

  f32x4 acc[4][4] = {};

  for (int k0 = 0; k0 < 1024; k0 += 64) {
    __syncthreads();  // previous iter's ds_reads done before overwrite
    gl2lds16(gA + k0,                  lA0);
    gl2lds16(gA + 64 * 1024 + k0,      lA0 + 4096);
    gl2lds16(gA + k0 + 32,             lA1);
    gl2lds16(gA + 64 * 1024 + k0 + 32, lA1 + 4096);
    gl2lds16(gB + k0,                  lB0);
    gl2lds16(gB + 64 * 1024 + k0,      lB0 + 4096);
    gl2lds16(gB + k0 + 32,             lB1);
    gl2lds16(gB + 64 * 1024 + k0 + 32, lB1 + 4096);
    __syncthreads();  // compiler drains vmcnt before barrier

    f16x8 ah[4], bh[4];
    // ---- half 0 (k0 .. k0+31) from sA0/sB0, r0 indexing ----
#pragma unroll
    for (int t = 0; t < 4; ++t) {
      int ar = (wm * 64 + t * 16 + fr) * 32 + kc * 8;
      int br = (wn * 64 + t * 16 + fr) * 32 + kc * 8;
      ah[t] = *(const f16x8*)&sA0[ar];
      bh[t] = *(const f16x8*)&sB0[br];
    }
#pragma unroll
    for (int mt = 0; mt < 4; ++mt)
#pragma unroll
      for (int nt = 0; nt < 4; ++nt)
        acc[mt][nt] = __builtin_amdgcn_mfma_f32_16x16x32_f16(
            ah[mt], bh[nt], acc[mt][nt], 0, 0, 0);
    // ---- half 1 (k0+32 .. k0+63) from sA1/sB1; reuse frag regs ----
#pragma unroll
    for (int t = 0; t < 4; ++t) {
      int ar = (wm * 64 + t * 16 + fr) * 32 + kc * 8;
      int br = (wn * 64 + t * 16 + fr) * 32 + kc * 8;
      ah[t] = *(const f16x8*)&sA1[ar];
      bh[t] = *(const f16x8*)&sB1[br];
    }
#pragma unroll
    for (int mt = 0; mt < 4; ++mt)
#pragma unroll
      for (int nt = 0; nt < 4; ++nt)
        acc[mt][nt] = __builtin_amdgcn_mfma_f32_16x16x32_f16(
            ah[mt], bh[nt], acc[mt][nt], 0, 0, 0);
  }

  // epilogue: C/D layout col(n)=lane&15, row(m)=(lane>>4)*4+reg
  const int seg = n0 >> 10;  // block-uniform
  const int mrow = (lane >> 4) * 4;
#pragma unroll
  for (int nt = 0; nt < 4; ++nt) {
    int n = n0 + wn * 64 + nt * 16 + fr;
    float bv = bcat[n];
#pragma unroll
    for (int mt = 0; mt < 4; ++mt) {
      int mbase = m0 + wm * 64 + mt * 16 + mrow;
      f32x4 a = acc[mt][nt];
#pragma unroll
      for (int r = 0; r < 4; ++r) {
        int m = mbase + r;
        float v = a[r] + bv;
        if (seg == 0) {
          Z[(size_t)m * 2048 + n] = (_Float16)expf(-expf(v));
        } else if (seg == 1) {
          Z[(size_t)m * 2048 + n] =
              (_Float16)(v * X[(size_t)m * 1024 + (n - 1024)]);
        } else {
          out[(size_t)m * 1024 + (n - 2048)] = v;
        }
      }
    }
  }
}

// ======================= chunked linear-recurrence scan =======================
// r3 scan kernels verbatim (tail best measured: 191 us).
#define LSEQ 4096
#define NC 64
#define LC 64
#define ZW 2048

// vectorized: 4 n's per thread (f16x4 = 8B loads, float4 stores), 256 thr
__global__ __launch_bounds__(256) void scan_chunk(const _Float16* __restrict__ Z,
                                                  float* __restrict__ ac,
                                                  float* __restrict__ uc) {
  int n4 = threadIdx.x * 4;
  int c = blockIdx.y;
  int b = blockIdx.z;
  const _Float16* base = Z + (size_t)(b * LSEQ + c * LC) * ZW;
  float a[4] = {1.0f, 1.0f, 1.0f, 1.0f};
  float u[4] = {0.0f, 0.0f, 0.0f, 0.0f};
#pragma unroll 4
  for (int l = 0; l < LC; ++l) {
    f16x4 ev = *(const f16x4*)&base[(size_t)l * ZW + n4];
    f16x4 bx = *(const f16x4*)&base[(size_t)l * ZW + 1024 + n4];
#pragma unroll
    for (int i = 0; i < 4; ++i) {
      float e = (float)ev[i];
      a[i] *= e;
      u[i] = fmaf(e, u[i], (float)bx[i]);
    }
  }
  size_t o = ((size_t)b * NC + c) * 1024 + n4;
  *(float4*)&ac[o] = make_float4(a[0], a[1], a[2], a[3]);
  *(float4*)&uc[o] = make_float4(u[0], u[1], u[2], u[3]);
}

__global__ __launch_bounds__(256) void scan_prefix(const float* __restrict__ ac,
                                                   const float* __restrict__ uc,
                                                   float* __restrict__ hin) {
  int idx = blockIdx.x * 256 + threadIdx.x;  // 0..4095
  int b = idx >> 10, n = idx & 1023;
  float h = 0.0f;
  for (int c = 0; c < NC; ++c) {
    size_t o = ((size_t)b * NC + c) * 1024 + n;
    hin[o] = h;
    h = fmaf(ac[o], h, uc[o]);
  }
}

__global__ __launch_bounds__(256) void scan_final(const _Float16* __restrict__ Z,
                                                  const float* __restrict__ hin,
                                                  float* __restrict__ out) {
  int n4 = threadIdx.x * 4;
  int c = blockIdx.y;
  int b = blockIdx.z;
  const _Float16* base = Z + (size_t)(b * LSEQ + c * LC) * ZW;
  float* obase = out + (size_t)(b * LSEQ + c * LC) * 1024;
  size_t ho = ((size_t)b * NC + c) * 1024 + n4;
  float4 hv = *(const float4*)&hin[ho];
  float h[4] = {hv.x, hv.y, hv.z, hv.w};
#pragma unroll 4
  for (int l = 0; l < LC; ++l) {
    f16x4 ev = *(const f16x4*)&base[(size_t)l * ZW + n4];
    f16x4 bx = *(const f16x4*)&base[(size_t)l * ZW + 1024 + n4];
    float4 cc = *(const float4*)&obase[(size_t)l * 1024 + n4];
#pragma unroll
    for (int i = 0; i < 4; ++i)
      h[i] = fmaf((float)ev[i], h[i], (float)bx[i]);
    *(float4*)&obase[(size_t)l * 1024 + n4] =
        make_float4(cc.x * h[0] * 4.0f, cc.y * h[1] * 4.0f,
                    cc.z * h[2] * 4.0f, cc.w * h[3] * 4.0f);
  }
}

// ======================= launch =======================
extern "C" void kernel_launch(void* const* d_in, const int* in_sizes, int n_in,
                              void* d_out, int out_size, void* d_ws, size_t ws_size,
                              hipStream_t stream) {
  const float* x    = (const float*)d_in[0];
  const float* Awmu = (const float*)d_in[1];
  const float* Awlv = (const float*)d_in[2];
  const float* Abmu = (const float*)d_in[3];
  const float* Ablv = (const float*)d_in[4];
  const float* Bwmu = (const float*)d_in[5];
  const float* Bwlv = (const float*)d_in[6];
  const float* Bbmu = (const float*)d_in[7];
  const float* Bblv = (const float*)d_in[8];
  const float* Cwmu = (const float*)d_in[9];
  const float* Cwlv = (const float*)d_in[10];
  const float* Cbmu = (const float*)d_in[11];
  const float* Cblv = (const float*)d_in[12];
  const float* Dwmu = (const float*)d_in[13];
  const float* Dwlv = (const float*)d_in[14];
  const float* Dbmu = (const float*)d_in[15];
  const float* Dblv = (const float*)d_in[16];

  uint32_t k4[4][2];
  for (uint32_t i = 0; i < 4; ++i)
    tf2x32(0u, 42u, 0u, i, k4[i][0], k4[i][1]);  // kA,kB,kC,kdt
  RngKeys kk;
  tf2x32(k4[0][0], k4[0][1], 0u, 0u, kk.wA0, kk.wA1);
  tf2x32(k4[0][0], k4[0][1], 0u, 1u, kk.bA0, kk.bA1);
  tf2x32(k4[1][0], k4[1][1], 0u, 0u, kk.wB0, kk.wB1);
  tf2x32(k4[1][0], k4[1][1], 0u, 1u, kk.bB0, kk.bB1);
  tf2x32(k4[2][0], k4[2][1], 0u, 0u, kk.wC0, kk.wC1);
  tf2x32(k4[2][0], k4[2][1], 0u, 1u, kk.bC0, kk.bC1);
  tf2x32(k4[3][0], k4[3][1], 0u, 0u, kk.wD0, kk.wD1);
  tf2x32(k4[3][0], k4[3][1], 0u, 1u, kk.bD0, kk.bD1);

  // workspace layout (~104 MiB live)
  // Scan temporaries (ac/uc/hin) ALIAS the Xh region: Xh is consumed only by
  // gemm_fused, which completes before scan_chunk; convert_x fully rewrites
  // Xh next iteration.
  char* ws = (char*)d_ws;
  const size_t OFF_WH   = 0;                    // 3072*1024*2 = 6 MiB
  const size_t OFF_BCAT = 6291456;              // 3072 f32
  const size_t OFF_XH   = 8388608;              // 16384*1024*2 = 32 MiB
  const size_t OFF_Z    = 41943040;             // 16384*2048*2 = 64 MiB
  const size_t OFF_AC   = OFF_XH;               // 4*NC*1024*4 = 1 MiB
  const size_t OFF_UC   = OFF_XH + 2097152;
  const size_t OFF_HIN  = OFF_XH + 4194304;
  const size_t NEEDED   = OFF_Z + (size_t)16384 * 2048 * 2;
  if (ws_size < NEEDED) return;

  _Float16* Wh  = (_Float16*)(ws + OFF_WH);
  float*    bcat= (float*)(ws + OFF_BCAT);
  _Float16* Xh  = (_Float16*)(ws + OFF_XH);
  _Float16* Z   = (_Float16*)(ws + OFF_Z);
  float*    ac  = (float*)(ws + OFF_AC);
  float*    ucv = (float*)(ws + OFF_UC);
  float*    hin = (float*)(ws + OFF_HIN);
  float*    out = (float*)d_out;

  gen_weights<<<dim3(12288), dim3(256), 0, stream>>>(
      Awmu, Awlv, Dwmu, Dwlv, Bwmu, Bwlv, Cwmu, Cwlv, Wh, kk);
  gen_bias<<<dim3(12), dim3(256), 0, stream>>>(
      Abmu, Ablv, Dbmu, Dblv, Bbmu, Bblv, Cbmu, Cblv, bcat, kk);
  convert_x<<<dim3(16384), dim3(256), 0, stream>>>(x, Xh);
  gemm_fused<<<dim3(24, 128), dim3(256), 0, stream>>>(
      Xh, Wh, x, bcat, Z, out);
  scan_chunk<<<dim3(1, NC, 4), dim3(256), 0, stream>>>(Z, ac, ucv);
  scan_prefix<<<dim3(16), dim3(256), 0, stream>>>(ac, ucv, hin);
  scan_final<<<dim3(1, NC, 4), dim3(256), 0, stream>>>(Z, hin, out);
}